// Round 13
// baseline (249.278 us; speedup 1.0000x reference)
//
#include <hip/hip_runtime.h>

typedef _Float16 f16;
typedef _Float16 f16x4 __attribute__((ext_vector_type(4)));
typedef _Float16 f16x8 __attribute__((ext_vector_type(8)));
typedef float f32x4 __attribute__((ext_vector_type(4)));
typedef int i32x4 __attribute__((ext_vector_type(4)));
typedef unsigned long long u64;

#define ALPHA 0.2f
#define NN 8192
#define DD 256
#define INVLN2 1.44269504088896f
#define MFMA16(a, b, c) __builtin_amdgcn_mfma_f32_16x16x32_f16(a, b, c, 0, 0, 0)

// ---------------- K0: prep — WT=f16(W^T), r1/r2, zero S + maxkey ----------------
__global__ __launch_bounds__(256) void k0_prep(const float* __restrict__ W,
                                               const float* __restrict__ a,
                                               f16* __restrict__ WT,
                                               float* __restrict__ r1,
                                               float* __restrict__ r2,
                                               float* __restrict__ S,
                                               unsigned* __restrict__ maxkey) {
    const int b = blockIdx.x;
    const int t = threadIdx.x;
    if (b < 16) {
        __shared__ f16 tl[16][256];
        const int k0 = b * 16;
        const int kr = t >> 4, cb = (t & 15) << 4;
        #pragma unroll
        for (int p = 0; p < 4; ++p) {
            float4 v = *(const float4*)&W[(k0 + kr) * DD + cb + p * 4];
            tl[kr][cb + p * 4 + 0] = (f16)v.x;
            tl[kr][cb + p * 4 + 1] = (f16)v.y;
            tl[kr][cb + p * 4 + 2] = (f16)v.z;
            tl[kr][cb + p * 4 + 3] = (f16)v.w;
        }
        __syncthreads();
        f16 outv[16];
        #pragma unroll
        for (int q = 0; q < 16; ++q) outv[q] = tl[q][t];
        *(f16x8*)&WT[t * DD + k0]     = *(f16x8*)&outv[0];
        *(f16x8*)&WT[t * DD + k0 + 8] = *(f16x8*)&outv[8];
    } else {
        __shared__ float al[256];
        al[t] = a[(b - 16) * DD + t];
        __syncthreads();
        float s = 0.f;
        for (int k = 0; k < DD; ++k) s = fmaf(W[t * DD + k], al[k], s);
        float* rr = (b == 16) ? r1 : r2;
        rr[t] = s * INVLN2;
        f32x4 z = {0.f, 0.f, 0.f, 0.f};
        float* sp = S + (b - 16) * 4096 + t * 16;
        *(f32x4*)(sp)      = z;
        *(f32x4*)(sp + 4)  = z;
        *(f32x4*)(sp + 8)  = z;
        *(f32x4*)(sp + 12) = z;
        if (b == 16 && t == 0) *maxkey = 0u;
    }
}

// ---------------- K1 (fused): blocks 0..511 = GEMM; 512.. = adj->bitmask pack ------
__global__ __launch_bounds__(256) void k1_fused(const float* __restrict__ h,
                                                const f16* __restrict__ WT,
                                                const float* __restrict__ r1,
                                                const float* __restrict__ r2,
                                                const int* __restrict__ adj,
                                                f16* __restrict__ WhT,
                                                float* __restrict__ Wh1,
                                                float* __restrict__ Wh2,
                                                unsigned* __restrict__ maxkey,
                                                unsigned* __restrict__ maskw) {
    const int bid = blockIdx.x;
    const int t   = threadIdx.x;
    const int lane = t & 63;
    const int w    = t >> 6;
    if (bid >= 512) {
        // -------- pack one adj row to bitmask (validated in r10) --------
        const int row = bid - 512;
        const int* arow = adj + (size_t)row * NN;
        unsigned* mrow  = maskw + (size_t)row * 256;
        for (int it = 0; it < 32; ++it) {
            const int j0 = (it * 4 + w) * 64;
            int v = arow[j0 + lane];
            u64 m = __ballot(v > 0);
            if (lane == 0) mrow[j0 >> 5]       = (unsigned)m;
            if (lane == 1) mrow[(j0 >> 5) + 1] = (unsigned)(m >> 32);
        }
        return;
    }
    // -------- GEMM: WhT = f16(h@W)^T; wave0 also Wh1/Wh2 + maxkey --------
    const int i0   = bid * 16;
    const int r    = lane & 15;
    const int hi   = lane >> 4;
    const int nbase = w * 64;

    f32x4 acc[4];
    #pragma unroll
    for (int nc = 0; nc < 4; ++nc) acc[nc] = (f32x4){0.f, 0.f, 0.f, 0.f};
    float s1 = 0.f, s2 = 0.f;

    const float* hrow = h + (size_t)(i0 + r) * DD;
    #pragma unroll
    for (int kt = 0; kt < 8; ++kt) {
        const int kb = kt * 32 + hi * 8;
        float4 h0 = *(const float4*)&hrow[kb];
        float4 h1 = *(const float4*)&hrow[kb + 4];
        f16x8 af;
        af[0] = (f16)h0.x; af[1] = (f16)h0.y; af[2] = (f16)h0.z; af[3] = (f16)h0.w;
        af[4] = (f16)h1.x; af[5] = (f16)h1.y; af[6] = (f16)h1.z; af[7] = (f16)h1.w;
        if (w == 0) {
            float4 ra0 = *(const float4*)&r1[kb];
            float4 ra1 = *(const float4*)&r1[kb + 4];
            float4 rb0 = *(const float4*)&r2[kb];
            float4 rb1 = *(const float4*)&r2[kb + 4];
            s1 += h0.x * ra0.x + h0.y * ra0.y + h0.z * ra0.z + h0.w * ra0.w
                + h1.x * ra1.x + h1.y * ra1.y + h1.z * ra1.z + h1.w * ra1.w;
            s2 += h0.x * rb0.x + h0.y * rb0.y + h0.z * rb0.z + h0.w * rb0.w
                + h1.x * rb1.x + h1.y * rb1.y + h1.z * rb1.z + h1.w * rb1.w;
        }
        #pragma unroll
        for (int nc = 0; nc < 4; ++nc) {
            f16x8 bf = *(const f16x8*)&WT[(nbase + nc * 16 + r) * DD + kb];
            acc[nc] = MFMA16(af, bf, acc[nc]);
        }
    }
    #pragma unroll
    for (int nc = 0; nc < 4; ++nc) {
        f16x4 o;
        o[0] = (f16)acc[nc][0]; o[1] = (f16)acc[nc][1];
        o[2] = (f16)acc[nc][2]; o[3] = (f16)acc[nc][3];
        *(f16x4*)&WhT[(size_t)(nbase + nc * 16 + r) * NN + i0 + hi * 4] = o;
    }
    if (w == 0) {
        s1 += __shfl_xor(s1, 16); s1 += __shfl_xor(s1, 32);
        s2 += __shfl_xor(s2, 16); s2 += __shfl_xor(s2, 32);
        if (lane < 16) {
            Wh1[i0 + lane] = s1;
            Wh2[i0 + lane] = s2;
            unsigned u = __float_as_uint(s2);
            u = (u & 0x80000000u) ? ~u : (u | 0x80000000u);
            atomicMax(maxkey, u);
        }
    }
}

// ---------------- K3: fused masked softmax + PV — all in-loop memory L2-class ------
// grid = 256 itiles x js_n, 256 thr (4 waves). Block: 32 i-rows, full n=256,
// j-steps of 64. P computed once by all threads (row=t>>3, jc=t&7) from the BITMASK
// -> 4KB XOR-swizzled LDS dbuf. Wave w: n [w*64,+64); A = P from LDS; B = WhT (L2).
// (mask,Wh2) 2-slot queue ages a full step; B issued at step top.
__device__ __forceinline__ f16x8 pcomp8(unsigned bits, float4 q0, float4 q1,
                                        float wh1r, float m_r, float& sacc) {
    float p[8];
    float e;
    e = wh1r + q0.x; e = fmaxf(e, ALPHA * e); p[0] = (bits & 1u)   ? exp2f(e - m_r) : 0.f;
    e = wh1r + q0.y; e = fmaxf(e, ALPHA * e); p[1] = (bits & 2u)   ? exp2f(e - m_r) : 0.f;
    e = wh1r + q0.z; e = fmaxf(e, ALPHA * e); p[2] = (bits & 4u)   ? exp2f(e - m_r) : 0.f;
    e = wh1r + q0.w; e = fmaxf(e, ALPHA * e); p[3] = (bits & 8u)   ? exp2f(e - m_r) : 0.f;
    e = wh1r + q1.x; e = fmaxf(e, ALPHA * e); p[4] = (bits & 16u)  ? exp2f(e - m_r) : 0.f;
    e = wh1r + q1.y; e = fmaxf(e, ALPHA * e); p[5] = (bits & 32u)  ? exp2f(e - m_r) : 0.f;
    e = wh1r + q1.z; e = fmaxf(e, ALPHA * e); p[6] = (bits & 64u)  ? exp2f(e - m_r) : 0.f;
    e = wh1r + q1.w; e = fmaxf(e, ALPHA * e); p[7] = (bits & 128u) ? exp2f(e - m_r) : 0.f;
    sacc += ((p[0] + p[1]) + (p[2] + p[3])) + ((p[4] + p[5]) + (p[6] + p[7]));
    f16x8 pk;
    pk[0] = (f16)p[0]; pk[1] = (f16)p[1]; pk[2] = (f16)p[2]; pk[3] = (f16)p[3];
    pk[4] = (f16)p[4]; pk[5] = (f16)p[5]; pk[6] = (f16)p[6]; pk[7] = (f16)p[7];
    return pk;
}

__global__ __launch_bounds__(256, 3) void k3_attn(const unsigned* __restrict__ maskw,
                                                  const f16* __restrict__ WhT,
                                                  const float* __restrict__ Wh1,
                                                  const float* __restrict__ Wh2,
                                                  const unsigned* __restrict__ maxkey,
                                                  float* __restrict__ D,
                                                  float* __restrict__ S,
                                                  int jrange, int jsmask, int jshift) {
    __shared__ __align__(16) f16 pbuf[2][32 * 64];    // 2 x 4 KB

    const int t     = threadIdx.x;
    const int lane  = t & 63;
    const int w     = t >> 6;
    const int js    = blockIdx.x & jsmask;
    const int itile = blockIdx.x >> jshift;
    const int i0    = itile * 32;
    const int jb0   = js * jrange;
    const int ns    = jrange >> 6;

    unsigned mk = *maxkey;
    const float maxW2 = __uint_as_float((mk & 0x80000000u) ? (mk & 0x7fffffffu) : ~mk);

    // phase-A role: row (0..31), jc (8 j's per step)
    const int row = t >> 3;
    const int jc  = t & 7;
    const float wh1r = Wh1[i0 + row];
    float tm = wh1r + maxW2;
    const float m_r = fmaxf(tm, ALPHA * tm);
    const unsigned* mrow = maskw + (size_t)(i0 + row) * 256 + (jb0 >> 5) + (jc >> 2);
    const int bsh = (jc & 3) * 8;
    const float* w2p = Wh2 + jc * 8;
    const int pwb = row * 128 + ((jc ^ (row & 7)) << 4);

    // phase-B role
    const int r  = lane & 15;
    const int hi = lane >> 4;
    const int nb = w * 64;
    const int rx = (r & 7) << 4;
    const f16* wbase = WhT + (size_t)(nb + r) * NN + jb0 + hi * 8;

    f32x4 acc[2][4];
    #pragma unroll
    for (int ic = 0; ic < 2; ++ic)
        #pragma unroll
        for (int nc = 0; nc < 4; ++nc) acc[ic][nc] = (f32x4){0.f, 0.f, 0.f, 0.f};
    float sacc = 0.f;

    // ---- prologue: P(0) -> pbuf[0]; queue (mask,Wh2) for step 1 ----
    {
        unsigned mw = mrow[0];
        float4 q0 = *(const float4*)(w2p + jb0);
        float4 q1 = *(const float4*)(w2p + jb0 + 4);
        f16x8 pk = pcomp8((mw >> bsh) & 255u, q0, q1, wh1r, m_r, sacc);
        *(f16x8*)((char*)pbuf[0] + pwb) = pk;
    }
    unsigned mU = 0;
    float4 qU0, qU1;
    if (ns > 1) {
        mU  = mrow[2];
        qU0 = *(const float4*)(w2p + jb0 + 64);
        qU1 = *(const float4*)(w2p + jb0 + 68);
    }
    __syncthreads();

    for (int s = 0; s < ns; ++s) {
        const int sel = s & 1;
        const int jb  = jb0 + (s << 6);
        const bool more = (s + 1 < ns);

        // (1) TOP: issue (mask,Wh2) for step s+2 — ages a full step
        unsigned mV = 0;
        float4 qV0, qV1;
        if (s + 2 < ns) {
            mV  = mrow[(s + 2) * 2];
            qV0 = *(const float4*)(w2p + jb + 128);
            qV1 = *(const float4*)(w2p + jb + 132);
        }
        // (2) B(WhT) loads for BOTH kt of this step (L2)
        f16x8 B[2][4];
        #pragma unroll
        for (int kt = 0; kt < 2; ++kt)
            #pragma unroll
            for (int nc = 0; nc < 4; ++nc)
                B[kt][nc] = *(const f16x8*)(wbase + (size_t)(nc * 16) * NN
                                            + (s << 6) + kt * 32);
        // (3) A(P) fragments from LDS
        f16x8 A[2][2];
        #pragma unroll
        for (int kt = 0; kt < 2; ++kt) {
            const int kb = (((kt * 4 + hi) << 4) ^ rx);
            A[kt][0] = *(const f16x8*)((const char*)pbuf[sel] + r * 128 + kb);
            A[kt][1] = *(const f16x8*)((const char*)pbuf[sel] + (16 + r) * 128 + kb);
        }
        // (4) compute P(s+1) from queued slot (VALU covers B latency), write LDS
        if (more) {
            f16x8 pk = pcomp8((mU >> bsh) & 255u, qU0, qU1, wh1r, m_r, sacc);
            *(f16x8*)((char*)pbuf[sel ^ 1] + pwb) = pk;
            mU = mV; qU0 = qV0; qU1 = qV1;
        }
        // (5) MFMA
        #pragma unroll
        for (int kt = 0; kt < 2; ++kt) {
            acc[0][0] = MFMA16(A[kt][0], B[kt][0], acc[0][0]);
            acc[0][1] = MFMA16(A[kt][0], B[kt][1], acc[0][1]);
            acc[0][2] = MFMA16(A[kt][0], B[kt][2], acc[0][2]);
            acc[0][3] = MFMA16(A[kt][0], B[kt][3], acc[0][3]);
            acc[1][0] = MFMA16(A[kt][1], B[kt][0], acc[1][0]);
            acc[1][1] = MFMA16(A[kt][1], B[kt][1], acc[1][1]);
            acc[1][2] = MFMA16(A[kt][1], B[kt][2], acc[1][2]);
            acc[1][3] = MFMA16(A[kt][1], B[kt][3], acc[1][3]);
        }
        __syncthreads();
    }

    // ---- row sums -> S (8 consecutive threads per row) ----
    sacc += __shfl_xor(sacc, 1);
    sacc += __shfl_xor(sacc, 2);
    sacc += __shfl_xor(sacc, 4);
    if ((t & 7) == 0) atomicAdd(&S[i0 + row], sacc);

    // ---- partial D -> private slab js: i = i0 + ic*16 + hi*4 + q, n = nb + nc*16 + r
    float* Dp = D + (size_t)js * NN * DD + (size_t)(i0 + hi * 4) * DD + nb + r;
    #pragma unroll
    for (int ic = 0; ic < 2; ++ic)
        #pragma unroll
        for (int nc = 0; nc < 4; ++nc)
            #pragma unroll
            for (int q = 0; q < 4; ++q)
                __builtin_nontemporal_store(acc[ic][nc][q],
                                            Dp + (size_t)(ic * 16 + q) * DD + nc * 16);
}

// ---------------- K4: sum slabs + normalize + ELU ----------------
__global__ __launch_bounds__(256) void k4_finish(const float* __restrict__ D,
                                                 const float* __restrict__ S,
                                                 float* __restrict__ out,
                                                 int nslab) {
    const int g   = blockIdx.x * 256 + threadIdx.x;
    const int rw  = g >> 6;
    const int c4  = (g & 63) << 2;
    const size_t off = ((size_t)rw << 8) + c4;
    f32x4 v = {0.f, 0.f, 0.f, 0.f};
    for (int s = 0; s < nslab; ++s)
        v += __builtin_nontemporal_load((const f32x4*)&D[off + (size_t)s * NN * DD]);
    const float inv = 1.0f / S[rw];
    f32x4 o;
    #pragma unroll
    for (int q = 0; q < 4; ++q) {
        float x = v[q] * inv;
        o[q] = (x > 0.f) ? x : (__expf(x) - 1.f);
    }
    *(f32x4*)&out[off] = o;
}

extern "C" void kernel_launch(void* const* d_in, const int* in_sizes, int n_in,
                              void* d_out, int out_size, void* d_ws, size_t ws_size,
                              hipStream_t stream) {
    const float* h   = (const float*)d_in[0];
    const int*   adj = (const int*)d_in[1];
    const float* W   = (const float*)d_in[2];
    const float* a   = (const float*)d_in[3];
    float* out = (float*)d_out;

    char* ws = (char*)d_ws;
    f16*      WT     = (f16*)ws;                        // 128 KB
    f16*      WhT    = (f16*)(ws + 131072);             // 4 MB
    float*    r1     = (float*)(ws + 4325376);          // 1 KB
    float*    r2     = (float*)(ws + 4326400);          // 1 KB
    float*    Wh1    = (float*)(ws + 4327424);          // 32 KB
    float*    Wh2    = (float*)(ws + 4360192);          // 32 KB
    unsigned* maxkey = (unsigned*)(ws + 4392960);       // 4 B (pad 256)
    float*    S      = (float*)(ws + 4393216);          // 32 KB
    unsigned* maskw  = (unsigned*)(ws + 4425984);       // 8 MB bitmask
    float*    D      = (float*)(ws + 12814592);         // js_n x 8 MB

    const size_t base = 12814592;
    const size_t slab = (size_t)NN * DD * 4;
    int js_n = 1, jshift = 0, jsmask = 0;
    if (ws_size >= base + 4 * slab)      { js_n = 4; jshift = 2; jsmask = 3; }
    else if (ws_size >= base + 2 * slab) { js_n = 2; jshift = 1; jsmask = 1; }
    const int jrange = NN / js_n;

    k0_prep<<<dim3(18), dim3(256), 0, stream>>>(W, a, WT, r1, r2, S, maxkey);
    k1_fused<<<dim3(8704), dim3(256), 0, stream>>>(h, WT, r1, r2, adj, WhT,
                                                   Wh1, Wh2, maxkey, maskw);
    k3_attn<<<dim3(js_n * 256), dim3(256), 0, stream>>>(maskw, WhT, Wh1, Wh2, maxkey,
                                                        D, S, jrange, jsmask, jshift);
    k4_finish<<<dim3(2048), dim3(256), 0, stream>>>(D, S, out, js_n);
}

// Round 14
// 212.807 us; speedup vs baseline: 1.1714x; 1.1714x over previous
//
#include <hip/hip_runtime.h>

typedef _Float16 f16;
typedef _Float16 f16x4 __attribute__((ext_vector_type(4)));
typedef _Float16 f16x8 __attribute__((ext_vector_type(8)));
typedef float f32x4 __attribute__((ext_vector_type(4)));
typedef int i32x4 __attribute__((ext_vector_type(4)));
typedef unsigned long long u64;

#define ALPHA 0.2f
#define NN 8192
#define DD 256
#define INVLN2 1.44269504088896f
#define MFMA16(a, b, c) __builtin_amdgcn_mfma_f32_16x16x32_f16(a, b, c, 0, 0, 0)

// ---------------- K0: prep — WT=f16(W^T), r1/r2, zero S + maxkey ----------------
__global__ __launch_bounds__(256) void k0_prep(const float* __restrict__ W,
                                               const float* __restrict__ a,
                                               f16* __restrict__ WT,
                                               float* __restrict__ r1,
                                               float* __restrict__ r2,
                                               float* __restrict__ S,
                                               unsigned* __restrict__ maxkey) {
    const int b = blockIdx.x;
    const int t = threadIdx.x;
    if (b < 16) {
        __shared__ f16 tl[16][256];
        const int k0 = b * 16;
        const int kr = t >> 4, cb = (t & 15) << 4;
        #pragma unroll
        for (int p = 0; p < 4; ++p) {
            float4 v = *(const float4*)&W[(k0 + kr) * DD + cb + p * 4];
            tl[kr][cb + p * 4 + 0] = (f16)v.x;
            tl[kr][cb + p * 4 + 1] = (f16)v.y;
            tl[kr][cb + p * 4 + 2] = (f16)v.z;
            tl[kr][cb + p * 4 + 3] = (f16)v.w;
        }
        __syncthreads();
        f16 outv[16];
        #pragma unroll
        for (int q = 0; q < 16; ++q) outv[q] = tl[q][t];
        *(f16x8*)&WT[t * DD + k0]     = *(f16x8*)&outv[0];
        *(f16x8*)&WT[t * DD + k0 + 8] = *(f16x8*)&outv[8];
    } else {
        __shared__ float al[256];
        al[t] = a[(b - 16) * DD + t];
        __syncthreads();
        float s = 0.f;
        for (int k = 0; k < DD; ++k) s = fmaf(W[t * DD + k], al[k], s);
        float* rr = (b == 16) ? r1 : r2;
        rr[t] = s * INVLN2;
        f32x4 z = {0.f, 0.f, 0.f, 0.f};
        float* sp = S + (b - 16) * 4096 + t * 16;
        *(f32x4*)(sp)      = z;
        *(f32x4*)(sp + 4)  = z;
        *(f32x4*)(sp + 8)  = z;
        *(f32x4*)(sp + 12) = z;
        if (b == 16 && t == 0) *maxkey = 0u;
    }
}

// ---------------- K1 (fused): blocks 0..511 = GEMM; 512.. = adj->bitmask pack ------
__global__ __launch_bounds__(256) void k1_fused(const float* __restrict__ h,
                                                const f16* __restrict__ WT,
                                                const float* __restrict__ r1,
                                                const float* __restrict__ r2,
                                                const int* __restrict__ adj,
                                                f16* __restrict__ WhT,
                                                float* __restrict__ Wh1,
                                                float* __restrict__ Wh2,
                                                unsigned* __restrict__ maxkey,
                                                unsigned* __restrict__ maskw) {
    const int bid = blockIdx.x;
    const int t   = threadIdx.x;
    const int lane = t & 63;
    const int w    = t >> 6;
    if (bid >= 512) {
        const int row = bid - 512;
        const int* arow = adj + (size_t)row * NN;
        unsigned* mrow  = maskw + (size_t)row * 256;
        for (int it = 0; it < 32; ++it) {
            const int j0 = (it * 4 + w) * 64;
            int v = arow[j0 + lane];
            u64 m = __ballot(v > 0);
            if (lane == 0) mrow[j0 >> 5]       = (unsigned)m;
            if (lane == 1) mrow[(j0 >> 5) + 1] = (unsigned)(m >> 32);
        }
        return;
    }
    const int i0   = bid * 16;
    const int r    = lane & 15;
    const int hi   = lane >> 4;
    const int nbase = w * 64;

    f32x4 acc[4];
    #pragma unroll
    for (int nc = 0; nc < 4; ++nc) acc[nc] = (f32x4){0.f, 0.f, 0.f, 0.f};
    float s1 = 0.f, s2 = 0.f;

    const float* hrow = h + (size_t)(i0 + r) * DD;
    #pragma unroll
    for (int kt = 0; kt < 8; ++kt) {
        const int kb = kt * 32 + hi * 8;
        float4 h0 = *(const float4*)&hrow[kb];
        float4 h1 = *(const float4*)&hrow[kb + 4];
        f16x8 af;
        af[0] = (f16)h0.x; af[1] = (f16)h0.y; af[2] = (f16)h0.z; af[3] = (f16)h0.w;
        af[4] = (f16)h1.x; af[5] = (f16)h1.y; af[6] = (f16)h1.z; af[7] = (f16)h1.w;
        if (w == 0) {
            float4 ra0 = *(const float4*)&r1[kb];
            float4 ra1 = *(const float4*)&r1[kb + 4];
            float4 rb0 = *(const float4*)&r2[kb];
            float4 rb1 = *(const float4*)&r2[kb + 4];
            s1 += h0.x * ra0.x + h0.y * ra0.y + h0.z * ra0.z + h0.w * ra0.w
                + h1.x * ra1.x + h1.y * ra1.y + h1.z * ra1.z + h1.w * ra1.w;
            s2 += h0.x * rb0.x + h0.y * rb0.y + h0.z * rb0.z + h0.w * rb0.w
                + h1.x * rb1.x + h1.y * rb1.y + h1.z * rb1.z + h1.w * rb1.w;
        }
        #pragma unroll
        for (int nc = 0; nc < 4; ++nc) {
            f16x8 bf = *(const f16x8*)&WT[(nbase + nc * 16 + r) * DD + kb];
            acc[nc] = MFMA16(af, bf, acc[nc]);
        }
    }
    #pragma unroll
    for (int nc = 0; nc < 4; ++nc) {
        f16x4 o;
        o[0] = (f16)acc[nc][0]; o[1] = (f16)acc[nc][1];
        o[2] = (f16)acc[nc][2]; o[3] = (f16)acc[nc][3];
        *(f16x4*)&WhT[(size_t)(nbase + nc * 16 + r) * NN + i0 + hi * 4] = o;
    }
    if (w == 0) {
        s1 += __shfl_xor(s1, 16); s1 += __shfl_xor(s1, 32);
        s2 += __shfl_xor(s2, 16); s2 += __shfl_xor(s2, 32);
        if (lane < 16) {
            Wh1[i0 + lane] = s1;
            Wh2[i0 + lane] = s2;
            unsigned u = __float_as_uint(s2);
            u = (u & 0x80000000u) ? ~u : (u | 0x80000000u);
            atomicMax(maxkey, u);
        }
    }
}

// ---------------- K3: m97-style fused masked softmax + PV ----------------
// grid = 64 itile x 2 nth x js_n, 256 thr (4 waves, 2iw x 2nw). Tile 128i x 128n,
// BK=64j, ns = jrange/64 steps. LDS 32KB single-buffered: P[128][64] + WhT[128][64],
// XOR-swizzled. 2 barriers/step; next-step staging loads issued at top of compute;
// ~3 blocks/CU cover barrier drains. P from mask bits (L2) + Wh2; WhT from L2.
__device__ __forceinline__ f16x8 pcomp8(unsigned bits, float4 q0, float4 q1,
                                        float wh1r, float m_r, float& sacc) {
    float p[8];
    float e;
    e = wh1r + q0.x; e = fmaxf(e, ALPHA * e); p[0] = (bits & 1u)   ? exp2f(e - m_r) : 0.f;
    e = wh1r + q0.y; e = fmaxf(e, ALPHA * e); p[1] = (bits & 2u)   ? exp2f(e - m_r) : 0.f;
    e = wh1r + q0.z; e = fmaxf(e, ALPHA * e); p[2] = (bits & 4u)   ? exp2f(e - m_r) : 0.f;
    e = wh1r + q0.w; e = fmaxf(e, ALPHA * e); p[3] = (bits & 8u)   ? exp2f(e - m_r) : 0.f;
    e = wh1r + q1.x; e = fmaxf(e, ALPHA * e); p[4] = (bits & 16u)  ? exp2f(e - m_r) : 0.f;
    e = wh1r + q1.y; e = fmaxf(e, ALPHA * e); p[5] = (bits & 32u)  ? exp2f(e - m_r) : 0.f;
    e = wh1r + q1.z; e = fmaxf(e, ALPHA * e); p[6] = (bits & 64u)  ? exp2f(e - m_r) : 0.f;
    e = wh1r + q1.w; e = fmaxf(e, ALPHA * e); p[7] = (bits & 128u) ? exp2f(e - m_r) : 0.f;
    sacc += ((p[0] + p[1]) + (p[2] + p[3])) + ((p[4] + p[5]) + (p[6] + p[7]));
    f16x8 pk;
    pk[0] = (f16)p[0]; pk[1] = (f16)p[1]; pk[2] = (f16)p[2]; pk[3] = (f16)p[3];
    pk[4] = (f16)p[4]; pk[5] = (f16)p[5]; pk[6] = (f16)p[6]; pk[7] = (f16)p[7];
    return pk;
}

__global__ __launch_bounds__(256) void k3_attn(const unsigned* __restrict__ maskw,
                                               const f16* __restrict__ WhT,
                                               const float* __restrict__ Wh1,
                                               const float* __restrict__ Wh2,
                                               const unsigned* __restrict__ maxkey,
                                               float* __restrict__ D,
                                               float* __restrict__ S,
                                               int jrange, int jsmask, int jshift) {
    __shared__ __align__(16) f16 wbuf[128 * 64];   // 16 KB
    __shared__ __align__(16) f16 pbuf[128 * 64];   // 16 KB

    const int t     = threadIdx.x;
    const int lane  = t & 63;
    const int w     = t >> 6;
    const int js    = blockIdx.x & jsmask;
    const int rem   = blockIdx.x >> jshift;
    const int nth   = rem & 1;
    const int itile = rem >> 1;
    const int i0    = itile * 128;
    const int jb0   = js * jrange;
    const int ns    = jrange >> 6;

    unsigned mk = *maxkey;
    const float maxW2 = __uint_as_float((mk & 0x80000000u) ? (mk & 0x7fffffffu) : ~mk);

    // P role: thread -> rows {pr, pr+64}, j-span [jq*16, jq*16+16) per step
    const int pr = t >> 2;
    const int jq = t & 3;
    const float wh1r0 = Wh1[i0 + pr];
    const float wh1r1 = Wh1[i0 + 64 + pr];
    float tm0 = wh1r0 + maxW2, tm1 = wh1r1 + maxW2;
    const float m0 = fmaxf(tm0, ALPHA * tm0);
    const float m1 = fmaxf(tm1, ALPHA * tm1);
    const unsigned* mrow0 = maskw + (size_t)(i0 + pr) * 256 + (jq >> 1);
    const unsigned* mrow1 = mrow0 + (size_t)64 * 256;
    const int msh  = (jq & 1) * 16;
    const float* w2p = Wh2 + jq * 16;
    const int psw  = pr & 7;
    const int pby0 = pr * 128;
    const int pby1 = (pr + 64) * 128;

    // WhT staging role: thread -> n-row sr, j-half jh (4 x 16B chunks)
    const int sr = t >> 1;
    const int jh = t & 1;
    const f16* wsrc = WhT + (size_t)(nth * 128 + sr) * NN + jh * 32;
    const int wby = sr * 128;
    const int ssw = sr & 7;

    // MFMA role: wave (iw, nw) owns 64i x 64n
    const int r  = lane & 15;
    const int hi = lane >> 4;
    const int iw = w >> 1;
    const int nw = w & 1;

    f32x4 acc[4][4];
    #pragma unroll
    for (int ic = 0; ic < 4; ++ic)
        #pragma unroll
        for (int nc = 0; nc < 4; ++nc) acc[ic][nc] = (f32x4){0.f, 0.f, 0.f, 0.f};
    float s0 = 0.f, s1 = 0.f;

    // staging registers (loaded in compute phase of previous step)
    i32x4 wv0, wv1, wv2, wv3;
    unsigned mA, mB;
    float4 q0, q1, q2, q3;
    {
        const int jb = jb0;
        wv0 = *(const i32x4*)(wsrc + jb);
        wv1 = *(const i32x4*)(wsrc + jb + 8);
        wv2 = *(const i32x4*)(wsrc + jb + 16);
        wv3 = *(const i32x4*)(wsrc + jb + 24);
        mA = mrow0[jb >> 5];
        mB = mrow1[jb >> 5];
        q0 = *(const float4*)(w2p + jb);
        q1 = *(const float4*)(w2p + jb + 4);
        q2 = *(const float4*)(w2p + jb + 8);
        q3 = *(const float4*)(w2p + jb + 12);
    }

    for (int s = 0; s < ns; ++s) {
        const int jb = jb0 + (s << 6);
        const bool more = (s + 1 < ns);

        // ---- STAGE: compute P, write P + WhT tiles into LDS ----
        unsigned bits0 = (mA >> msh) & 0xffffu;
        unsigned bits1 = (mB >> msh) & 0xffffu;
        f16x8 pA0 = pcomp8(bits0 & 255u, q0, q1, wh1r0, m0, s0);
        f16x8 pA1 = pcomp8(bits0 >> 8,   q2, q3, wh1r0, m0, s0);
        f16x8 pB0 = pcomp8(bits1 & 255u, q0, q1, wh1r1, m1, s1);
        f16x8 pB1 = pcomp8(bits1 >> 8,   q2, q3, wh1r1, m1, s1);
        *(f16x8*)((char*)pbuf + pby0 + (((jq * 2    ) ^ psw) << 4)) = pA0;
        *(f16x8*)((char*)pbuf + pby0 + (((jq * 2 + 1) ^ psw) << 4)) = pA1;
        *(f16x8*)((char*)pbuf + pby1 + (((jq * 2    ) ^ psw) << 4)) = pB0;
        *(f16x8*)((char*)pbuf + pby1 + (((jq * 2 + 1) ^ psw) << 4)) = pB1;
        *(i32x4*)((char*)wbuf + wby + (((jh * 4    ) ^ ssw) << 4)) = wv0;
        *(i32x4*)((char*)wbuf + wby + (((jh * 4 + 1) ^ ssw) << 4)) = wv1;
        *(i32x4*)((char*)wbuf + wby + (((jh * 4 + 2) ^ ssw) << 4)) = wv2;
        *(i32x4*)((char*)wbuf + wby + (((jh * 4 + 3) ^ ssw) << 4)) = wv3;
        __syncthreads();

        // ---- COMPUTE: issue next staging loads FIRST (age across MFMA+barrier) ----
        if (more) {
            const int jn = jb + 64;
            wv0 = *(const i32x4*)(wsrc + jn);
            wv1 = *(const i32x4*)(wsrc + jn + 8);
            wv2 = *(const i32x4*)(wsrc + jn + 16);
            wv3 = *(const i32x4*)(wsrc + jn + 24);
            mA = mrow0[jn >> 5];
            mB = mrow1[jn >> 5];
            q0 = *(const float4*)(w2p + jn);
            q1 = *(const float4*)(w2p + jn + 4);
            q2 = *(const float4*)(w2p + jn + 8);
            q3 = *(const float4*)(w2p + jn + 12);
        }

        #pragma unroll
        for (int kt = 0; kt < 2; ++kt) {
            f16x8 A[4], B[4];
            #pragma unroll
            for (int ic = 0; ic < 4; ++ic) {
                const int row = iw * 64 + ic * 16 + r;
                A[ic] = *(const f16x8*)((const char*)pbuf + row * 128
                          + (((kt * 4 + hi) ^ (row & 7)) << 4));
            }
            #pragma unroll
            for (int nc = 0; nc < 4; ++nc) {
                const int row = nw * 64 + nc * 16 + r;
                B[nc] = *(const f16x8*)((const char*)wbuf + row * 128
                          + (((kt * 4 + hi) ^ (row & 7)) << 4));
            }
            #pragma unroll
            for (int ic = 0; ic < 4; ++ic)
                #pragma unroll
                for (int nc = 0; nc < 4; ++nc)
                    acc[ic][nc] = MFMA16(A[ic], B[nc], acc[ic][nc]);
        }
        __syncthreads();
    }

    // ---- row sums -> S (4 threads per row; nth==0 commits only) ----
    s0 += __shfl_xor(s0, 1); s0 += __shfl_xor(s0, 2);
    s1 += __shfl_xor(s1, 1); s1 += __shfl_xor(s1, 2);
    if (nth == 0 && jq == 0) {
        atomicAdd(&S[i0 + pr], s0);
        atomicAdd(&S[i0 + 64 + pr], s1);
    }

    // ---- partial D -> slab js: i = i0+iw*64+ic*16+hi*4+q, n = nth*128+nw*64+nc*16+r
    float* Dp = D + (size_t)js * NN * DD
              + (size_t)(i0 + iw * 64 + hi * 4) * DD + nth * 128 + nw * 64 + r;
    #pragma unroll
    for (int ic = 0; ic < 4; ++ic)
        #pragma unroll
        for (int nc = 0; nc < 4; ++nc)
            #pragma unroll
            for (int q = 0; q < 4; ++q)
                __builtin_nontemporal_store(acc[ic][nc][q],
                    Dp + (size_t)(ic * 16 + q) * DD + nc * 16);
}

// ---------------- K4: sum slabs + normalize + ELU ----------------
__global__ __launch_bounds__(256) void k4_finish(const float* __restrict__ D,
                                                 const float* __restrict__ S,
                                                 float* __restrict__ out,
                                                 int nslab) {
    const int g   = blockIdx.x * 256 + threadIdx.x;
    const int rw  = g >> 6;
    const int c4  = (g & 63) << 2;
    const size_t off = ((size_t)rw << 8) + c4;
    f32x4 v = {0.f, 0.f, 0.f, 0.f};
    for (int s = 0; s < nslab; ++s)
        v += __builtin_nontemporal_load((const f32x4*)&D[off + (size_t)s * NN * DD]);
    const float inv = 1.0f / S[rw];
    f32x4 o;
    #pragma unroll
    for (int q = 0; q < 4; ++q) {
        float x = v[q] * inv;
        o[q] = (x > 0.f) ? x : (__expf(x) - 1.f);
    }
    *(f32x4*)&out[off] = o;
}

extern "C" void kernel_launch(void* const* d_in, const int* in_sizes, int n_in,
                              void* d_out, int out_size, void* d_ws, size_t ws_size,
                              hipStream_t stream) {
    const float* h   = (const float*)d_in[0];
    const int*   adj = (const int*)d_in[1];
    const float* W   = (const float*)d_in[2];
    const float* a   = (const float*)d_in[3];
    float* out = (float*)d_out;

    char* ws = (char*)d_ws;
    f16*      WT     = (f16*)ws;                        // 128 KB
    f16*      WhT    = (f16*)(ws + 131072);             // 4 MB
    float*    r1     = (float*)(ws + 4325376);          // 1 KB
    float*    r2     = (float*)(ws + 4326400);          // 1 KB
    float*    Wh1    = (float*)(ws + 4327424);          // 32 KB
    float*    Wh2    = (float*)(ws + 4360192);          // 32 KB
    unsigned* maxkey = (unsigned*)(ws + 4392960);       // 4 B (pad 256)
    float*    S      = (float*)(ws + 4393216);          // 32 KB
    unsigned* maskw  = (unsigned*)(ws + 4425984);       // 8 MB bitmask
    float*    D      = (float*)(ws + 12814592);         // js_n x 8 MB

    const size_t base = 12814592;
    const size_t slab = (size_t)NN * DD * 4;
    int js_n = 2, jshift = 1, jsmask = 1;
    if (ws_size >= base + 8 * slab)      { js_n = 8; jshift = 3; jsmask = 7; }
    else if (ws_size >= base + 4 * slab) { js_n = 4; jshift = 2; jsmask = 3; }
    const int jrange = NN / js_n;

    k0_prep<<<dim3(18), dim3(256), 0, stream>>>(W, a, WT, r1, r2, S, maxkey);
    k1_fused<<<dim3(8704), dim3(256), 0, stream>>>(h, WT, r1, r2, adj, WhT,
                                                   Wh1, Wh2, maxkey, maskw);
    k3_attn<<<dim3(js_n * 128), dim3(256), 0, stream>>>(maskw, WhT, Wh1, Wh2, maxkey,
                                                        D, S, jrange, jsmask, jshift);
    k4_finish<<<dim3(2048), dim3(256), 0, stream>>>(D, S, out, js_n);
}